// Round 10
// baseline (119.815 us; speedup 1.0000x reference)
//
#include <hip/hip_runtime.h>

// 100x100 sliding mean over x[32][1][1124][1124] f32 -> out[32][1][1025][1025] f32.
// Pass H: horizontal 100-sum -> T (f16, stride 1032) in d_ws. Three-level LDS
//   partials (srow -> ps sums-of-4 -> qs sliding sums-of-16): 7 uniform LDS
//   reads per thread instead of 25 (hslide was LDS-issue-bound).
// Pass V: vertical 100-sum + 1e-4 scale. FULL-WIDTH blocks: one block spans
//   the entire 1025-col row (256 thr x f16x4 = 2050 B contiguous per row
//   visit) so the row-walk is two perfectly sequential DRAM streams; the
//   half-row strips of R9 wasted ~50% of every DRAM page. 13 bands (lowest
//   halo amp measured), batch-8 steady loads, NT out stores.

#define H_IN    1124
#define W_IN    1124
#define KWIN    100
#define W_OUT   1025
#define H_OUT   1025
#define TSTR    1032   // T row stride in halves (2064 B -> rows 16B-aligned)
#define NBANDS  13
#define BANDR   79     // 13*79 = 1027 >= 1025

typedef float    f32x4 __attribute__((ext_vector_type(4)));
typedef _Float16 f16x4 __attribute__((ext_vector_type(4)));

struct alignas(8) h4 { _Float16 a, b, c, d; };

// ---------------- Pass H: one block per input row, f16 T output -------------
__global__ __launch_bounds__(256) void hslide_kernel(
    const float* __restrict__ x,     // [g*1124][1124]
    _Float16* __restrict__ T)        // [g*1124][TSTR]
{
    __shared__ float srow[W_IN];     // 1124 floats
    __shared__ float ps[284];        // ps[j] = srow[4j..4j+3], j < 281
    __shared__ float qs[280];        // qs[j] = ps[j]+ps[j+1]+ps[j+2]+ps[j+3]

    const int row = blockIdx.x;
    const int tid = threadIdx.x;
    const f32x4* xr4 = (const f32x4*)(x + (size_t)row * W_IN);

    for (int i = tid; i < 281; i += 256)
        ((f32x4*)srow)[i] = __builtin_nontemporal_load(xr4 + i);
    __syncthreads();

    // level 1: sums of 4
    f32x4 lo = ((const f32x4*)srow)[tid];
    const float myps = lo[0] + lo[1] + lo[2] + lo[3];
    ps[tid] = myps;
    float myps2 = 0.f;
    if (tid < 25) {
        f32x4 v = ((const f32x4*)srow)[256 + tid];
        myps2 = v[0] + v[1] + v[2] + v[3];
        ps[256 + tid] = myps2;
    }
    __syncthreads();

    // level 2: sliding sums of 16 (4 consecutive ps)
    qs[tid] = myps + ps[tid + 1] + ps[tid + 2] + ps[tid + 3];
    if (tid < 22)
        qs[256 + tid] = myps2 + ps[257 + tid] + ps[258 + tid] + ps[259 + tid];
    __syncthreads();

    // 100-tap sums + slide, outputs w0 = 4*tid .. +3
    _Float16* trow = T + (size_t)row * TSTR;
    {
        float s = ps[tid + 24];
        #pragma unroll
        for (int i = 0; i < 6; ++i) s += qs[tid + 4 * i];   // ps[tid..tid+23]
        f32x4 hi = ((const f32x4*)srow)[tid + 25];          // srow[4t+100..+103]
        float s1 = s  + hi[0] - lo[0];
        float s2 = s1 + hi[1] - lo[1];
        float s3 = s2 + hi[2] - lo[2];
        *(h4*)(trow + 4 * tid) = h4{ (_Float16)s, (_Float16)s1,
                                     (_Float16)s2, (_Float16)s3 };
        if (tid == 255) {                                   // col 1024 + zero pads
            float t = ps[280];
            #pragma unroll
            for (int i = 0; i < 6; ++i) t += qs[256 + 4 * i];
            *(h4*)(trow + 1024) = h4{ (_Float16)t, (_Float16)0.f,
                                      (_Float16)0.f, (_Float16)0.f };
            *(h4*)(trow + 1028) = h4{ (_Float16)0.f, (_Float16)0.f,
                                      (_Float16)0.f, (_Float16)0.f };
        }
    }
}

// ---------------- Pass V: full-width blocks, contiguous row-walk ------------
// grid (NBANDS, g), block 256. Thread owns cols 4*tid..+3; lane 255 also owns
// col 1024 via scalar adds (pad cols are zero). Every row visit reads the
// whole 2050-B T row contiguously.
__global__ __launch_bounds__(256) void vslide_kernel(
    const _Float16* __restrict__ T,  // [g*1124][TSTR]
    float* __restrict__ out)         // [g][1025][1025]
{
    const int tid  = threadIdx.x;
    const int band = blockIdx.x;
    const int b    = blockIdx.y;
    const int r0   = band * BANDR;
    const int nr   = min(BANDR, H_OUT - r0);
    if (nr <= 0) return;

    const int w0 = tid * 4;
    const bool xtra = (tid == 255);                 // w0 == 1020, also col 1024
    const float scale = 1.0f / (float)(KWIN * KWIN);

    const _Float16* base = T + ((size_t)b * H_IN + r0) * TSTR + w0;

    float s0 = 0.f, s1 = 0.f, s2 = 0.f, s3 = 0.f, s8 = 0.f;

    // ---- prologue: rows r0..r0+99, batches of 8 independent 8B loads ----
    {
        const _Float16* p = base;
        for (int cg = 0; cg < 12; ++cg) {           // 96 rows
            f16x4 v[8];
            #pragma unroll
            for (int j = 0; j < 8; ++j)
                v[j] = *(const f16x4*)(p + (size_t)j * TSTR);
            #pragma unroll
            for (int j = 0; j < 8; ++j) {
                s0 += (float)v[j][0]; s1 += (float)v[j][1];
                s2 += (float)v[j][2]; s3 += (float)v[j][3];
            }
            if (xtra) {
                #pragma unroll
                for (int j = 0; j < 8; ++j)
                    s8 += (float)*(p + (size_t)j * TSTR + 4);
            }
            p += (size_t)8 * TSTR;
        }
        #pragma unroll
        for (int j = 0; j < 4; ++j) {               // 4 remaining rows
            f16x4 v = *(const f16x4*)(p + (size_t)j * TSTR);
            s0 += (float)v[0]; s1 += (float)v[1];
            s2 += (float)v[2]; s3 += (float)v[3];
            if (xtra) s8 += (float)*(p + (size_t)j * TSTR + 4);
        }
    }

    float* q = out + ((size_t)b * H_OUT + r0) * W_OUT + w0;
    __builtin_nontemporal_store(s0 * scale, q + 0);
    __builtin_nontemporal_store(s1 * scale, q + 1);
    __builtin_nontemporal_store(s2 * scale, q + 2);
    __builtin_nontemporal_store(s3 * scale, q + 3);
    if (xtra) __builtin_nontemporal_store(s8 * scale, q + 4);   // col 1024
    q += W_OUT;

    // ---- steady: batches of 8 steps (16 loads in flight), then remainder ---
    const _Float16* pa = base + (size_t)KWIN * TSTR;
    const _Float16* pd = base;
    const int steps = nr - 1;
    int i = 0;
    for (; i + 8 <= steps; i += 8) {
        f16x4 a[8], d[8];
        #pragma unroll
        for (int j = 0; j < 8; ++j) {
            a[j] = *(const f16x4*)(pa + (size_t)j * TSTR);
            d[j] = *(const f16x4*)(pd + (size_t)j * TSTR);
        }
        #pragma unroll
        for (int j = 0; j < 8; ++j) {
            s0 += (float)a[j][0] - (float)d[j][0];
            s1 += (float)a[j][1] - (float)d[j][1];
            s2 += (float)a[j][2] - (float)d[j][2];
            s3 += (float)a[j][3] - (float)d[j][3];
            __builtin_nontemporal_store(s0 * scale, q + 0);
            __builtin_nontemporal_store(s1 * scale, q + 1);
            __builtin_nontemporal_store(s2 * scale, q + 2);
            __builtin_nontemporal_store(s3 * scale, q + 3);
            if (xtra) {
                s8 += (float)*(pa + (size_t)j * TSTR + 4)
                    - (float)*(pd + (size_t)j * TSTR + 4);
                __builtin_nontemporal_store(s8 * scale, q + 4);
            }
            q += W_OUT;
        }
        pa += (size_t)8 * TSTR;
        pd += (size_t)8 * TSTR;
    }
    for (; i < steps; ++i) {
        f16x4 a = *(const f16x4*)pa, d = *(const f16x4*)pd;
        s0 += (float)a[0] - (float)d[0];
        s1 += (float)a[1] - (float)d[1];
        s2 += (float)a[2] - (float)d[2];
        s3 += (float)a[3] - (float)d[3];
        __builtin_nontemporal_store(s0 * scale, q + 0);
        __builtin_nontemporal_store(s1 * scale, q + 1);
        __builtin_nontemporal_store(s2 * scale, q + 2);
        __builtin_nontemporal_store(s3 * scale, q + 3);
        if (xtra) {
            s8 += (float)*(pa + 4) - (float)*(pd + 4);
            __builtin_nontemporal_store(s8 * scale, q + 4);
        }
        pa += TSTR; pd += TSTR; q += W_OUT;
    }
}

extern "C" void kernel_launch(void* const* d_in, const int* in_sizes, int n_in,
                              void* d_out, int out_size, void* d_ws, size_t ws_size,
                              hipStream_t stream) {
    const float* x = (const float*)d_in[0];
    float* out     = (float*)d_out;
    _Float16* ws   = (_Float16*)d_ws;

    const int B = 32;
    const size_t perBatchT = (size_t)H_IN * TSTR * sizeof(_Float16);  // ~2.32 MB

    int G = (int)(ws_size / perBatchT);
    if (G > B) G = B;
    if (G < 1) G = 1;

    for (int b0 = 0; b0 < B; b0 += G) {
        const int g = (B - b0 < G) ? (B - b0) : G;

        hslide_kernel<<<g * H_IN, 256, 0, stream>>>(
            x + (size_t)b0 * H_IN * W_IN, ws);

        dim3 vgrid(NBANDS, g);
        vslide_kernel<<<vgrid, 256, 0, stream>>>(
            ws, out + (size_t)b0 * H_OUT * W_OUT);
    }
}